// Round 1
// baseline (27.052 us; speedup 1.0000x reference)
//
#include <hip/hip_runtime.h>

// MultiVariatePoly: out[n] = b + sum_{i0,i1,i2,i3} W[((i0*8+i1)*8+i2)*8+i3]
//                              * P_{i0}(x0) P_{i1}(x1) P_{i2}(x2) P_{i3}(x3)
// Factorized contraction: 4096+512+64+8 fp32 FMAs per point.
// N = 65536 -> 1024 waves -> exactly 1 wave/SIMD on 256 CUs.

constexpr int NPOLY = 8;  // ORDER+1

__global__ __launch_bounds__(256) void mvpoly_kernel(
    const float* __restrict__ x,
    const float* __restrict__ W,
    const float* __restrict__ bias,
    float* __restrict__ out,
    int N)
{
    const int n = blockIdx.x * 256 + threadIdx.x;
    if (n >= N) return;

    // x is (N,4) row-major fp32 -> one coalesced 16B load per thread
    const float4 xv = reinterpret_cast<const float4*>(x)[n];

    // Legendre P_0..P_7 for dims 1..3, fully unrolled (compile-time indexed
    // -> stays in VGPRs, no scratch)
    float p1[NPOLY], p2[NPOLY], p3[NPOLY];
    p1[0] = 1.f; p1[1] = xv.y;
    p2[0] = 1.f; p2[1] = xv.z;
    p3[0] = 1.f; p3[1] = xv.w;
    #pragma unroll
    for (int k = 1; k < NPOLY - 1; ++k) {
        const float a = (2.f * k + 1.f) / (float)(k + 1);  // folds to constant
        const float c = (float)k / (float)(k + 1);
        p1[k + 1] = a * xv.y * p1[k] - c * p1[k - 1];
        p2[k + 1] = a * xv.z * p2[k] - c * p2[k - 1];
        p3[k + 1] = a * xv.w * p3[k] - c * p3[k - 1];
    }

    // Outer dim-0 loop is a runtime loop (keeps I$ footprint ~5 KB);
    // P0 is streamed via the recurrence in two scalars (no runtime array idx).
    float acc0 = 0.f;
    float P0prev = 0.f, P0cur = 1.f;
    const float x0 = xv.x;

    for (int i0 = 0; i0 < NPOLY; ++i0) {
        // wave-uniform base -> W loads should scalarize to s_load via K$
        const float* __restrict__ wb = W + i0 * (NPOLY * NPOLY * NPOLY);
        float acc1 = 0.f;
        #pragma unroll
        for (int i1 = 0; i1 < NPOLY; ++i1) {
            float acc2 = 0.f;
            #pragma unroll
            for (int i2 = 0; i2 < NPOLY; ++i2) {
                float acc3 = 0.f;
                #pragma unroll
                for (int i3 = 0; i3 < NPOLY; ++i3) {
                    acc3 = fmaf(wb[i1 * 64 + i2 * 8 + i3], p3[i3], acc3);
                }
                acc2 = fmaf(acc3, p2[i2], acc2);
            }
            acc1 = fmaf(acc2, p1[i1], acc1);
        }
        acc0 = fmaf(acc1, P0cur, acc0);

        // advance P0: P_{i0+1} = ((2*i0+1)*x0*P_i0 - i0*P_{i0-1}) / (i0+1)
        const float nf = (float)i0;
        const float pn = ((2.f * nf + 1.f) * x0 * P0cur - nf * P0prev) / (nf + 1.f);
        P0prev = P0cur;
        P0cur = pn;
    }

    out[n] = acc0 + bias[0];
}

extern "C" void kernel_launch(void* const* d_in, const int* in_sizes, int n_in,
                              void* d_out, int out_size, void* d_ws, size_t ws_size,
                              hipStream_t stream) {
    const float* x = (const float*)d_in[0];
    const float* W = (const float*)d_in[1];
    const float* b = (const float*)d_in[2];
    float* out = (float*)d_out;

    const int N = in_sizes[0] / 4;  // 65536 points, 4 coords each
    const int block = 256;
    const int grid = (N + block - 1) / block;

    hipLaunchKernelGGL(mvpoly_kernel, dim3(grid), dim3(block), 0, stream,
                       x, W, b, out, N);
}

// Round 2
// 19.560 us; speedup vs baseline: 1.3830x; 1.3830x over previous
//
#include <hip/hip_runtime.h>
#include <hip/hip_bf16.h>

// out[n] = b + sum_{i0..i3} W[((i0*8+i1)*8+i2)*8+i3] * P_i0(x0)P_i1(x1)P_i2(x2)P_i3(x3)
// Reformulated: c=(i0*8+i1), j=(i2*8+i3)
//   f23[n][j] = P2[j>>3]*P3[j&7]          (built per point, bf16)
//   G[n][c]   = sum_j f23[n][j]*W2[c][j]  (GEMM M=N_pts, N=64, K=64 -> MFMA)
//   out[n]    = sum_c P0[c>>3]*P1[c&7]*G[n][c] + b   (in-register Horner)
// Per wave: 64 points, 4 M-tiles x 4 N-tiles x 2 K-halves of mfma_f32_16x16x32_bf16.
// W staged once per block into LDS (bf16, 8KB). f23 LDS region reused for G.

typedef short short8 __attribute__((ext_vector_type(8)));
typedef float floatx4 __attribute__((ext_vector_type(4)));

static __device__ inline unsigned short f2bs(float f) {
    return __builtin_bit_cast(unsigned short, __float2bfloat16(f));
}
static __device__ inline unsigned pk(float a, float b) {
    return (unsigned)f2bs(a) | ((unsigned)f2bs(b) << 16);
}

__global__ __launch_bounds__(256, 1) void mvpoly_mfma(
    const float* __restrict__ x,
    const float* __restrict__ W,
    const float* __restrict__ bias,
    float* __restrict__ out,
    int N)
{
    // Wb: W2 as bf16 [64 rows c][64 cols j], row = 8 uint4 chunks, XOR-swizzled
    //     chunk_idx = c*8 + (chunk ^ (c&7))   (T2-style, kills stride-128B conflicts)
    // F23: per-wave f23 bf16 [64 pts][64 j], same layout; REUSED for G after MFMAs.
    __shared__ uint4 Wb[64 * 8];        // 8 KB
    __shared__ uint4 F23[4][64 * 8];    // 32 KB

    const int tid  = threadIdx.x;
    const int wid  = tid >> 6;
    const int lane = tid & 63;
    const int l15  = lane & 15;
    const int l4   = lane >> 4;
    const int n    = blockIdx.x * 256 + tid;
    const int nc   = (n < N) ? n : (N - 1);

    // ---- stage W -> LDS bf16 (block-cooperative, once) ----
    {
        const int c  = tid >> 2;           // row 0..63
        const int j0 = (tid & 3) * 16;     // col start 0/16/32/48
        const float4* ws = reinterpret_cast<const float4*>(W + c * 64 + j0);
        float4 w0 = ws[0], w1 = ws[1], w2 = ws[2], w3 = ws[3];
        uint4 ch0, ch1;
        ch0.x = pk(w0.x, w0.y); ch0.y = pk(w0.z, w0.w);
        ch0.z = pk(w1.x, w1.y); ch0.w = pk(w1.z, w1.w);
        ch1.x = pk(w2.x, w2.y); ch1.y = pk(w2.z, w2.w);
        ch1.z = pk(w3.x, w3.y); ch1.w = pk(w3.z, w3.w);
        const int sw = c & 7;
        Wb[c * 8 + (((j0 >> 3) + 0) ^ sw)] = ch0;
        Wb[c * 8 + (((j0 >> 3) + 1) ^ sw)] = ch1;
    }

    // ---- per-point Legendre polys (fp32, fully unrolled) ----
    const float4 xv = reinterpret_cast<const float4*>(x)[nc];
    float p0[8], p1[8], p2[8], p3[8];
    p0[0] = p1[0] = p2[0] = p3[0] = 1.f;
    p0[1] = xv.x; p1[1] = xv.y; p2[1] = xv.z; p3[1] = xv.w;
    #pragma unroll
    for (int k = 1; k < 7; ++k) {
        const float a = (2.f * k + 1.f) / (float)(k + 1);
        const float c = (float)k / (float)(k + 1);
        p0[k + 1] = a * xv.x * p0[k] - c * p0[k - 1];
        p1[k + 1] = a * xv.y * p1[k] - c * p1[k - 1];
        p2[k + 1] = a * xv.z * p2[k] - c * p2[k - 1];
        p3[k + 1] = a * xv.w * p3[k] - c * p3[k - 1];
    }

    // ---- f23 row for own point (lane-local) -> LDS bf16, swizzled ----
    uint4* f23w = F23[wid];
    const int sw = lane & 7;
    #pragma unroll
    for (int e = 0; e < 8; ++e) {          // chunk e: j = e*8..e*8+7, i2 = e
        const float s2 = p2[e];
        uint4 ch;
        ch.x = pk(s2 * p3[0], s2 * p3[1]);
        ch.y = pk(s2 * p3[2], s2 * p3[3]);
        ch.z = pk(s2 * p3[4], s2 * p3[5]);
        ch.w = pk(s2 * p3[6], s2 * p3[7]);
        f23w[lane * 8 + (e ^ sw)] = ch;
    }

    __syncthreads();   // Wb visible block-wide (f23 is wave-local)

    // ---- load fragments ----
    // A (f23): lane supplies row m = mt*16 + (lane&15), k = kh*32 + (lane>>4)*8 + e
    // B (W2^T): lane supplies col c = nt*16 + (lane&15), k = j likewise; B[j][c]=W2[c][j]
    short8 bfrag[8], afrag[8];
    #pragma unroll
    for (int nt = 0; nt < 4; ++nt) {
        #pragma unroll
        for (int kh = 0; kh < 2; ++kh) {
            const int c  = nt * 16 + l15;
            const int ch = (kh * 4 + l4) ^ (c & 7);
            bfrag[nt * 2 + kh] = *reinterpret_cast<const short8*>(&Wb[c * 8 + ch]);
        }
    }
    #pragma unroll
    for (int mt = 0; mt < 4; ++mt) {
        #pragma unroll
        for (int kh = 0; kh < 2; ++kh) {
            const int m  = mt * 16 + l15;
            const int ch = (kh * 4 + l4) ^ (m & 7);
            afrag[mt * 2 + kh] = *reinterpret_cast<const short8*>(&f23w[m * 8 + ch]);
        }
    }

    // ---- MFMA: G[64 pts][64 c] in fp32 accumulators ----
    floatx4 acc[4][4];
    #pragma unroll
    for (int mt = 0; mt < 4; ++mt)
        #pragma unroll
        for (int nt = 0; nt < 4; ++nt)
            acc[mt][nt] = floatx4{0.f, 0.f, 0.f, 0.f};
    #pragma unroll
    for (int mt = 0; mt < 4; ++mt) {
        #pragma unroll
        for (int nt = 0; nt < 4; ++nt) {
            acc[mt][nt] = __builtin_amdgcn_mfma_f32_16x16x32_bf16(
                afrag[mt * 2 + 0], bfrag[nt * 2 + 0], acc[mt][nt], 0, 0, 0);
            acc[mt][nt] = __builtin_amdgcn_mfma_f32_16x16x32_bf16(
                afrag[mt * 2 + 1], bfrag[nt * 2 + 1], acc[mt][nt], 0, 0, 0);
        }
    }

    // ---- write G (bf16) into reused f23 region ----
    // C/D layout (m89-verified): col = lane&15, row = (lane>>4)*4 + q
    // All f23 reads (afrag) completed before these stores; wave-local region,
    // per-wave in-order DS pipeline makes this safe without a barrier.
    {
        unsigned short* gb = reinterpret_cast<unsigned short*>(f23w);
        #pragma unroll
        for (int mt = 0; mt < 4; ++mt) {
            #pragma unroll
            for (int nt = 0; nt < 4; ++nt) {
                #pragma unroll
                for (int q = 0; q < 4; ++q) {
                    const int row  = mt * 16 + l4 * 4 + q;
                    const int col  = nt * 16 + l15;
                    const int bidx = (row * 128 + ((col * 2) ^ ((row & 7) << 4))) >> 1;
                    gb[bidx] = f2bs(acc[mt][nt][q]);
                }
            }
        }
    }

    // ---- epilogue: own point's G row x f01 (in-register) ----
    float res = 0.f;
    #pragma unroll
    for (int e = 0; e < 8; ++e) {          // chunk e: c = e*8..e*8+7 -> i0 = e
        const uint4 ch = f23w[lane * 8 + (e ^ sw)];
        const unsigned u[4] = {ch.x, ch.y, ch.z, ch.w};
        float inner = 0.f;
        #pragma unroll
        for (int t = 0; t < 4; ++t) {
            const float lo = __builtin_bit_cast(float, u[t] << 16);
            const float hi = __builtin_bit_cast(float, u[t] & 0xFFFF0000u);
            inner = fmaf(p1[2 * t],     lo, inner);
            inner = fmaf(p1[2 * t + 1], hi, inner);
        }
        res = fmaf(p0[e], inner, res);
    }

    if (n < N) out[n] = res + bias[0];
}

extern "C" void kernel_launch(void* const* d_in, const int* in_sizes, int n_in,
                              void* d_out, int out_size, void* d_ws, size_t ws_size,
                              hipStream_t stream) {
    const float* x = (const float*)d_in[0];
    const float* W = (const float*)d_in[1];
    const float* b = (const float*)d_in[2];
    float* out = (float*)d_out;

    const int N = in_sizes[0] / 4;          // 65536 points
    const int grid = (N + 255) / 256;       // 256 blocks -> 1 per CU

    hipLaunchKernelGGL(mvpoly_mfma, dim3(grid), dim3(256), 0, stream,
                       x, W, b, out, N);
}

// Round 3
// 9.723 us; speedup vs baseline: 2.7824x; 2.0119x over previous
//
#include <hip/hip_runtime.h>
#include <hip/hip_bf16.h>

// out[n] = b + sum_{i0..i3} W[((i0*8+i1)*8+i2)*8+i3] * P_i0(x0)..P_i3(x3)
// c=(i0*8+i1), j=(i2*8+i3):  G[n][c] = sum_j f23[n][j] * W2[c][j]  (MFMA)
//                            out[n]  = sum_c p0[c>>3]*p1[c&7]*G[n][c] + b
//
// R3 restructure: 16 points per WAVE (was 64) -> 4096 waves = 4/SIMD (was 1).
// 4 lanes per point; redundant poly compute makes the MFMA A-fragment
// lane-local (A[row=l15][k=l4*8+e] = p2[kh*4+l4]*p3[e]) -> no f23 LDS at all.
// W staged once per block to LDS (bf16, XOR-swizzled). G kept fp32 through a
// per-wave stride-21 LDS transpose buffer for the epilogue.

typedef short short8 __attribute__((ext_vector_type(8)));
typedef float floatx4 __attribute__((ext_vector_type(4)));

static __device__ inline unsigned short f2bs(float f) {
    return __builtin_bit_cast(unsigned short, __float2bfloat16(f));
}
static __device__ inline unsigned pk(float a, float b) {
    return (unsigned)f2bs(a) | ((unsigned)f2bs(b) << 16);
}

__global__ __launch_bounds__(256, 4) void mvpoly3(
    const float* __restrict__ x,
    const float* __restrict__ W,
    const float* __restrict__ bias,
    float* __restrict__ out,
    int N)
{
    __shared__ uint4 Wb[64 * 8];        // W2 bf16, row c = 8 chunks, chunk ^= (c&7)
    __shared__ float Gt[4][64 * 21];    // per-wave G^T: addr = c*21 + r (stride 21
                                        // makes both write & read <=2-way conflicts)

    const int tid  = threadIdx.x;
    const int wid  = tid >> 6;
    const int lane = tid & 63;
    const int l15  = lane & 15;
    const int l4   = lane >> 4;

    // ---- stage W -> LDS bf16 (block-cooperative; loads issued first so the
    //      HBM/L2 latency overlaps the poly VALU below) ----
    {
        const int c  = tid >> 2;
        const int j0 = (tid & 3) * 16;
        const float4* ws = reinterpret_cast<const float4*>(W + c * 64 + j0);
        float4 w0 = ws[0], w1 = ws[1], w2 = ws[2], w3 = ws[3];
        uint4 ch0, ch1;
        ch0.x = pk(w0.x, w0.y); ch0.y = pk(w0.z, w0.w);
        ch0.z = pk(w1.x, w1.y); ch0.w = pk(w1.z, w1.w);
        ch1.x = pk(w2.x, w2.y); ch1.y = pk(w2.z, w2.w);
        ch1.z = pk(w3.x, w3.y); ch1.w = pk(w3.z, w3.w);
        const int sw = c & 7;
        Wb[c * 8 + (((j0 >> 3) + 0) ^ sw)] = ch0;
        Wb[c * 8 + (((j0 >> 3) + 1) ^ sw)] = ch1;
    }

    // ---- own point's Legendre polys (4x redundant across l4 groups) ----
    const int pbase = blockIdx.x * 64 + wid * 16;
    int p = pbase + l15;
    if (p >= N) p = N - 1;
    const float4 xv = reinterpret_cast<const float4*>(x)[p];

    float p0[8], p1[8], p2[8], p3[8];
    p0[0] = p1[0] = p2[0] = p3[0] = 1.f;
    p0[1] = xv.x; p1[1] = xv.y; p2[1] = xv.z; p3[1] = xv.w;
    #pragma unroll
    for (int k = 1; k < 7; ++k) {
        const float a = (2.f * k + 1.f) / (float)(k + 1);
        const float c = (float)k / (float)(k + 1);
        p0[k + 1] = a * xv.x * p0[k] - c * p0[k - 1];
        p1[k + 1] = a * xv.y * p1[k] - c * p1[k - 1];
        p2[k + 1] = a * xv.z * p2[k] - c * p2[k - 1];
        p3[k + 1] = a * xv.w * p3[k] - c * p3[k - 1];
    }

    // ---- lane-local A-fragments: A[row=l15][k = kh*32 + l4*8 + e] ----
    // p2[kh*4+l4] via cndmask chains (no runtime array index -> no scratch)
    const float s2a = (l4 == 0) ? p2[0] : (l4 == 1) ? p2[1] : (l4 == 2) ? p2[2] : p2[3];
    const float s2b = (l4 == 0) ? p2[4] : (l4 == 1) ? p2[5] : (l4 == 2) ? p2[6] : p2[7];
    uint4 fa0, fa1;
    fa0.x = pk(s2a * p3[0], s2a * p3[1]); fa0.y = pk(s2a * p3[2], s2a * p3[3]);
    fa0.z = pk(s2a * p3[4], s2a * p3[5]); fa0.w = pk(s2a * p3[6], s2a * p3[7]);
    fa1.x = pk(s2b * p3[0], s2b * p3[1]); fa1.y = pk(s2b * p3[2], s2b * p3[3]);
    fa1.z = pk(s2b * p3[4], s2b * p3[5]); fa1.w = pk(s2b * p3[6], s2b * p3[7]);
    const short8 af0 = __builtin_bit_cast(short8, fa0);
    const short8 af1 = __builtin_bit_cast(short8, fa1);

    __syncthreads();   // Wb ready

    // ---- B-fragments from LDS + MFMA: G[16 pts][64 c] fp32 ----
    floatx4 acc[4];
    #pragma unroll
    for (int nt = 0; nt < 4; ++nt) acc[nt] = floatx4{0.f, 0.f, 0.f, 0.f};

    #pragma unroll
    for (int nt = 0; nt < 4; ++nt) {
        const int c = nt * 16 + l15;
        const short8 bf0 = *reinterpret_cast<const short8*>(&Wb[c * 8 + ((0 * 4 + l4) ^ (c & 7))]);
        const short8 bf1 = *reinterpret_cast<const short8*>(&Wb[c * 8 + ((1 * 4 + l4) ^ (c & 7))]);
        acc[nt] = __builtin_amdgcn_mfma_f32_16x16x32_bf16(af0, bf0, acc[nt], 0, 0, 0);
        acc[nt] = __builtin_amdgcn_mfma_f32_16x16x32_bf16(af1, bf1, acc[nt], 0, 0, 0);
    }

    // ---- G^T (fp32) to per-wave LDS: row r = l4*4+q (C/D layout), col c ----
    float* gt = Gt[wid];
    #pragma unroll
    for (int nt = 0; nt < 4; ++nt) {
        #pragma unroll
        for (int q = 0; q < 4; ++q) {
            gt[(nt * 16 + l15) * 21 + (l4 * 4 + q)] = acc[nt][q];
        }
    }
    // (wave-local region; per-wave in-order DS pipeline orders write->read)

    // ---- epilogue: lane reduces quarter c-range [l4*16, l4*16+16) of point l15 ----
    // i0 = c>>3 = l4*2 + (cc>>3) -> two cndmask-selected p0 values; i1 = cc&7.
    const float s0a = (l4 == 0) ? p0[0] : (l4 == 1) ? p0[2] : (l4 == 2) ? p0[4] : p0[6];
    const float s0b = (l4 == 0) ? p0[1] : (l4 == 1) ? p0[3] : (l4 == 2) ? p0[5] : p0[7];

    float part = 0.f;
    #pragma unroll
    for (int cc = 0; cc < 16; ++cc) {
        const float g  = gt[(l4 * 16 + cc) * 21 + l15];
        const float f0 = (cc < 8) ? s0a : s0b;
        part = fmaf(g * p1[cc & 7], f0, part);
    }
    part += __shfl_xor(part, 16, 64);
    part += __shfl_xor(part, 32, 64);

    if (l4 == 0) {
        const int po = pbase + l15;
        if (po < N) out[po] = part + bias[0];
    }
}

extern "C" void kernel_launch(void* const* d_in, const int* in_sizes, int n_in,
                              void* d_out, int out_size, void* d_ws, size_t ws_size,
                              hipStream_t stream) {
    const float* x = (const float*)d_in[0];
    const float* W = (const float*)d_in[1];
    const float* b = (const float*)d_in[2];
    float* out = (float*)d_out;

    const int N = in_sizes[0] / 4;          // 65536 points
    const int grid = (N + 63) / 64;         // 64 points per 256-thread block -> 1024 blocks

    hipLaunchKernelGGL(mvpoly3, dim3(grid), dim3(256), 0, stream,
                       x, W, b, out, N);
}